// Round 1
// baseline (321.644 us; speedup 1.0000x reference)
//
#include <hip/hip_runtime.h>
#include <hip/hip_bf16.h>
#include <stdint.h>

// BConv2d: out = conv2d(sign(x), sign(w), pad=1) + b
// N=32, Cin=256, H=W=56, Cout=256, K=3. fp32 in/out.
//
// Approach: bit-pack signs (bit=1 <=> value>=0 <=> +1), then
// dot(±1,±1) over a 256-bit tap = 256 - 2*popcount(xor).
// Zero padding: OOB taps packed as all-zero bits (== all -1); the false
// contribution (256 - 2*pop(w_tap)) is removed via a per-(border-type,co)
// correction table precomputed in the weight-pack kernel.

#define NBATCH 32
#define CIN    256
#define COUT   256
#define HH     56
#define WW     56
#define HW     (HH*WW)          // 3136
#define NPIX   (NBATCH*HW)      // 100352
#define CO_CHUNK 64

// workspace layout
#define XP_WORDS ((size_t)NPIX * 8)            // 8 x u32 per pixel (256 bits)
#define WP_WORDS ((size_t)COUT * 9 * 8)        // per co: 9 taps x 8 u32
#define XP_BYTES (XP_WORDS * 4)                // 3,211,264
#define WP_BYTES (WP_WORDS * 4)                // 73,728

__global__ __launch_bounds__(256) void pack_x_kernel(
    const float* __restrict__ x, uint32_t* __restrict__ xp)
{
    int pix = blockIdx.x * 256 + threadIdx.x;   // 392*256 == NPIX exactly
    int n  = pix / HW;
    int hw = pix - n * HW;
    const float* xb = x + (size_t)n * CIN * HW + hw;

    uint32_t wordsv[8];
    #pragma unroll
    for (int wd = 0; wd < 8; ++wd) {
        uint32_t acc = 0;
        #pragma unroll 8
        for (int bt = 0; bt < 32; ++bt) {
            float v = xb[(size_t)(wd * 32 + bt) * HW];
            acc |= (v >= 0.0f ? 1u : 0u) << bt;
        }
        wordsv[wd] = acc;
    }
    uint4* dst = (uint4*)(xp + (size_t)pix * 8);
    dst[0] = make_uint4(wordsv[0], wordsv[1], wordsv[2], wordsv[3]);
    dst[1] = make_uint4(wordsv[4], wordsv[5], wordsv[6], wordsv[7]);
}

__global__ __launch_bounds__(256) void pack_w_kernel(
    const float* __restrict__ w, uint32_t* __restrict__ wp,
    float* __restrict__ corr)
{
    int co = blockIdx.x * 256 + threadIdx.x;
    if (co >= COUT) return;
    const float* wb = w + (size_t)co * CIN * 9;

    int pop0=0,pop1=0,pop2=0,pop3=0,pop4=0,pop5=0,pop6=0,pop7=0,pop8=0;
    int popv[9]; // filled with static indices below

    #pragma unroll
    for (int wd = 0; wd < 8; ++wd) {
        uint32_t acc[9];
        #pragma unroll
        for (int t = 0; t < 9; ++t) acc[t] = 0;
        for (int bt = 0; bt < 32; ++bt) {
            int ci = wd * 32 + bt;
            #pragma unroll
            for (int t = 0; t < 9; ++t) {
                float v = wb[(size_t)ci * 9 + t];
                acc[t] |= (v >= 0.0f ? 1u : 0u) << bt;
            }
        }
        #pragma unroll
        for (int t = 0; t < 9; ++t) {
            wp[((size_t)co * 9 + t) * 8 + wd] = acc[t];
        }
        pop0 += __popc(acc[0]); pop1 += __popc(acc[1]); pop2 += __popc(acc[2]);
        pop3 += __popc(acc[3]); pop4 += __popc(acc[4]); pop5 += __popc(acc[5]);
        pop6 += __popc(acc[6]); pop7 += __popc(acc[7]); pop8 += __popc(acc[8]);
    }
    popv[0]=pop0; popv[1]=pop1; popv[2]=pop2; popv[3]=pop3; popv[4]=pop4;
    popv[5]=pop5; popv[6]=pop6; popv[7]=pop7; popv[8]=pop8;

    // corr[btype][co]: btype = ht*3+wt; tap t: dh=t/3 (0..2 -> -1..+1), dw=t%3
    #pragma unroll
    for (int ht = 0; ht < 3; ++ht) {
        #pragma unroll
        for (int wt = 0; wt < 3; ++wt) {
            float c = 0.0f;
            #pragma unroll
            for (int t = 0; t < 9; ++t) {
                int dh = t / 3, dw = t % 3;
                bool inv = (ht == 0 && dh == 0) || (ht == 2 && dh == 2) ||
                           (wt == 0 && dw == 0) || (wt == 2 && dw == 2);
                if (inv) c += (float)(CIN - 2 * popv[t]);
            }
            corr[(ht * 3 + wt) * COUT + co] = c;
        }
    }
}

__global__ __launch_bounds__(256) void bconv_kernel(
    const uint32_t* __restrict__ xp, const uint32_t* __restrict__ wp,
    const float* __restrict__ corr, const float* __restrict__ bias,
    float* __restrict__ out)
{
    int pix = blockIdx.x * 256 + threadIdx.x;    // 392 blocks -> exactly NPIX
    int co0 = blockIdx.y * CO_CHUNK;

    int n  = pix / HW;
    int hw = pix - n * HW;
    int h  = hw / WW;
    int w_ = hw - h * WW;

    // load 9 taps x 8 words of packed x (zero for OOB taps)
    uint32_t xb[9][8];
    #pragma unroll
    for (int t = 0; t < 9; ++t) {
        int dh = t / 3 - 1, dw = t % 3 - 1;
        int hh = h + dh, ww = w_ + dw;
        if ((unsigned)hh < HH && (unsigned)ww < WW) {
            const uint4* src = (const uint4*)(xp + ((size_t)(n * HW + hh * WW + ww)) * 8);
            uint4 a = src[0];
            uint4 b4 = src[1];
            xb[t][0] = a.x;  xb[t][1] = a.y;  xb[t][2] = a.z;  xb[t][3] = a.w;
            xb[t][4] = b4.x; xb[t][5] = b4.y; xb[t][6] = b4.z; xb[t][7] = b4.w;
        } else {
            #pragma unroll
            for (int j = 0; j < 8; ++j) xb[t][j] = 0;
        }
    }

    int ht = (h == 0) ? 0 : ((h == HH - 1) ? 2 : 1);
    int wt = (w_ == 0) ? 0 : ((w_ == WW - 1) ? 2 : 1);
    const float* corr_b = corr + (ht * 3 + wt) * COUT;

    float* outp = out + (size_t)n * COUT * HW + hw;

    for (int c = 0; c < CO_CHUNK; ++c) {
        int co = co0 + c;
        const uint32_t* wrow = wp + (size_t)co * 72;   // uniform -> scalar loads
        int pop = 0;
        #pragma unroll
        for (int t = 0; t < 9; ++t) {
            #pragma unroll
            for (int j = 0; j < 8; ++j) {
                pop += __popc(xb[t][j] ^ wrow[t * 8 + j]);
            }
        }
        float val = (float)(2304 - 2 * pop) - corr_b[co] + bias[co];
        outp[(size_t)co * HW] = val;
    }
}

extern "C" void kernel_launch(void* const* d_in, const int* in_sizes, int n_in,
                              void* d_out, int out_size, void* d_ws, size_t ws_size,
                              hipStream_t stream) {
    const float* x = (const float*)d_in[0];
    const float* w = (const float*)d_in[1];
    const float* b = (const float*)d_in[2];
    float* out = (float*)d_out;

    uint32_t* xp   = (uint32_t*)d_ws;
    uint32_t* wpck = (uint32_t*)((char*)d_ws + XP_BYTES);
    float*    corr = (float*)((char*)d_ws + XP_BYTES + WP_BYTES);

    pack_x_kernel<<<NPIX / 256, 256, 0, stream>>>(x, xp);
    pack_w_kernel<<<1, 256, 0, stream>>>(w, wpck, corr);

    dim3 grid(NPIX / 256, COUT / CO_CHUNK);
    bconv_kernel<<<grid, 256, 0, stream>>>(xp, wpck, corr, b, out);
}